// Round 8
// baseline (245.852 us; speedup 1.0000x reference)
//
#include <hip/hip_runtime.h>

typedef float f4    __attribute__((ext_vector_type(4)));
typedef float f32x4 __attribute__((ext_vector_type(4)));
typedef short short8 __attribute__((ext_vector_type(8)));
typedef unsigned short u16;
typedef unsigned short u16x4 __attribute__((ext_vector_type(4)));

#define NCHUNK 24   // 768 k / 32 per chunk

// ---- ws fragment layouts (u16 units) — R7-verified ----
// A_ws[g:16][c:24][hl:2][rt:4][kq:4][r:16][ki:8]
//   strides: ki 1, r 8, kq 128, rt 512, hl 2048, c 4096, g 98304
// W_ws[c:24][panel:2][hl:2][rt:48][kq:4][r:16][ki:8]
//   strides: rt 512, hl 24576, panel 49152, c 98304
#define AWS_U16 1572864u   // 3.0 MB
#define WWS_U16 2359296u   // 4.5 MB

__device__ inline u16 f2bf(float x) {
    union { float f; unsigned u; } v; v.f = x;
    return (u16)((v.u + 0x7FFFu + ((v.u >> 16) & 1u)) >> 16);
}
__device__ inline float bf2f(u16 h) {
    union { unsigned u; float f; } v; v.u = ((unsigned)h) << 16;
    return v.f;
}

// Streaming pre-convert (R7-verbatim, verified): f32 -> bf16 hi/lo in fragment order.
__global__ __launch_bounds__(512) void convert_kernel(
    const float* __restrict__ A1, const float* __restrict__ A2,
    const float* __restrict__ W, u16* __restrict__ Aws, u16* __restrict__ Wws)
{
    const int id = blockIdx.x * 512 + threadIdx.x;
    if (blockIdx.x < 384) {
        const int u   = id;
        const int row = u / 192;
        const int k   = (u - row * 192) * 4;
        const float* src = (row < 512) ? (A1 + (size_t)row * 768 + k)
                                       : (A2 + (size_t)(row - 512) * 768 + k);
        const f4 v = *(const f4*)src;
        u16x4 h, l;
        #pragma unroll
        for (int j = 0; j < 4; ++j) { h[j] = f2bf(v[j]); l[j] = f2bf(v[j] - bf2f(h[j])); }
        const int g = row >> 6, rt = (row >> 4) & 3, r = row & 15;
        const int c = k >> 5, kq = (k >> 3) & 3, ki0 = k & 7;
        const size_t base = (size_t)g * 98304 + c * 4096 + rt * 512 + kq * 128 + r * 8 + ki0;
        *(u16x4*)&Aws[base]        = h;
        *(u16x4*)&Aws[base + 2048] = l;
    } else {
        const int u   = id - 384 * 512;
        const int o   = u % 768;
        const int kk4 = u / 768;
        const int kk  = kk4 * 4;
        const int z   = (kk4 >= 192);
        const int k   = kk - z * 768;
        u16x4 h, l;
        #pragma unroll
        for (int j = 0; j < 4; ++j) {
            const float v = W[(size_t)(kk + j) * 768 + o];
            h[j] = f2bf(v); l[j] = f2bf(v - bf2f(h[j]));
        }
        const int rt = o >> 4, r = o & 15;
        const int c = k >> 5, kq = (k >> 3) & 3, ki0 = k & 7;
        const size_t base = (size_t)c * 98304 + (size_t)z * 49152
                          + rt * 512 + kq * 128 + r * 8 + ki0;
        *(u16x4*)&Wws[base]         = h;
        *(u16x4*)&Wws[base + 24576] = l;
    }
}

// MFMA GEMM, fragments loaded DIRECTLY ws->VGPR (no LDS staging, no k-loop barriers).
// R7 evidence: staging was a pure copy-through costing ~13us of DS-pipe + 2 barriers x24
// chunks of 8-wave lockstep. ws addresses are already per-lane fragment addresses
// (base + lane*16B, coalesced); each wave reads its own A rt and the shared B window
// straight from L2-resident ws (~220 MB demand over the phase ~= 22 TB/s < 34 TB/s L2).
// Waves run barrier-free until the C-park; compiler pipelines 10 loads vs 12 MFMAs/chunk.
// Park + egress = R6/R7-verbatim (proven).
__global__ __launch_bounds__(512) void mfma_direct_kernel(
    const u16* __restrict__ Aws, const u16* __restrict__ Wws,
    const float* __restrict__ bias, float* __restrict__ out)
{
    __shared__ float p[128][68];            // rows 0-63: p1[n][o], 64-127: p2[m][o]

    const int o0 = blockIdx.x * 64;         // 12 o-slices
    const int nm = blockIdx.y;              // 16 (b, n-half, m-half) bricks
    const int b  = nm >> 2, hn = (nm >> 1) & 1, hm = nm & 1;
    const int n0 = hn * 64, m0 = hm * 64;
    const int g_n = b * 2 + hn;             // A1 ws group
    const int g_m = 8 + b * 2 + hm;         // A2 ws group
    const int t = threadIdx.x, lane = t & 63, w = t >> 6;
    const int rt0 = blockIdx.x * 4;         // W rt window

    // per-wave fragment base addresses (u16 units); all loads 16B-aligned, lane-coalesced
    const u16* aBase = Aws + (size_t)((w < 4) ? g_n : g_m) * 98304
                     + (w & 3) * 512 + lane * 8;
    const u16* bBase = Wws + (size_t)((w < 4) ? 0 : 1) * 49152
                     + rt0 * 512 + lane * 8;

    f32x4 acc[4] = {0, 0, 0, 0};

    #pragma unroll 2
    for (int c = 0; c < NCHUNK; ++c) {
        const u16* ap = aBase + (size_t)c * 4096;
        const u16* bp = bBase + (size_t)c * 98304;
        const short8 ah = *(const short8*)(ap);          // hl=0
        const short8 al = *(const short8*)(ap + 2048);   // hl=1
        #pragma unroll
        for (int ct = 0; ct < 4; ++ct) {
            const short8 bh = *(const short8*)(bp + ct * 512);
            const short8 bl = *(const short8*)(bp + 24576 + ct * 512);
            acc[ct] = __builtin_amdgcn_mfma_f32_16x16x32_bf16(ah, bh, acc[ct], 0, 0, 0);
            acc[ct] = __builtin_amdgcn_mfma_f32_16x16x32_bf16(ah, bl, acc[ct], 0, 0, 0);
            acc[ct] = __builtin_amdgcn_mfma_f32_16x16x32_bf16(al, bh, acc[ct], 0, 0, 0);
        }
    }

    // park C (verified D mapping: row=(lane>>4)*4+i, col=lane&15); first LDS use -> no
    // barrier needed before, one after
    #pragma unroll
    for (int ct = 0; ct < 4; ++ct)
        #pragma unroll
        for (int i = 0; i < 4; ++i)
            p[w * 16 + (lane >> 4) * 4 + i][ct * 16 + (lane & 15)] = acc[ct][i];
    __syncthreads();

    // egress (R6/R7-verbatim): thread -> (2 n-rows, all 64 m, one f4 of o)
    const int o4 = (t & 15) * 4;
    const int nn = t >> 4;                  // 0..31
    const f4 bb  = *(const f4*)(bias + o0 + o4);
    const f4 p1a = *(const f4*)&p[nn * 2 + 0][o4] + bb;
    const f4 p1b = *(const f4*)&p[nn * 2 + 1][o4] + bb;

    float* ob = out + ((size_t)(b * 128 + n0 + nn * 2) * 128 + m0) * 768 + o0 + o4;
    const size_t nstride = (size_t)128 * 768;

    #pragma unroll 4
    for (int m = 0; m < 64; ++m) {
        const f4 p2v = *(const f4*)&p[64 + m][o4];
        __builtin_nontemporal_store(p1a + p2v, (f4*)(ob + (size_t)m * 768));
        __builtin_nontemporal_store(p1b + p2v, (f4*)(ob + nstride + (size_t)m * 768));
    }
}

// ---------------- fallback: R6 kernel verbatim (passed @ absmax 0.015625) ----------------
__global__ __launch_bounds__(512) void fused_v6(
    const float* __restrict__ A1, const float* __restrict__ A2,
    const float* __restrict__ W, const float* __restrict__ bias,
    float* __restrict__ out)
{
    __shared__ union {
        struct { u16 Ah[4096], Al[4096], Bh[4096], Bl[4096]; } s;
        float p[128][68];
    } u;

    const int o0 = blockIdx.x * 64;
    const int nm = blockIdx.y;
    const int b  = nm >> 2;
    const int n0 = ((nm >> 1) & 1) * 64;
    const int m0 = (nm & 1) * 64;
    const int t = threadIdx.x, lane = t & 63, w = t >> 6;

    const float* aptr[2]; int a_dst[2];
    #pragma unroll
    for (int q = 0; q < 2; ++q) {
        const int a = t + q * 512, rc = a >> 3, k0 = (a & 7) * 4;
        const float* base = (rc < 64) ? (A1 + (size_t)(b * 128 + n0 + rc) * 768)
                                      : (A2 + (size_t)(b * 128 + m0 + (rc - 64)) * 768);
        aptr[q] = base + k0;
        a_dst[q] = (rc >> 4) * 512 + (k0 >> 3) * 128 + (rc & 15) * 8 + (k0 & 7);
    }
    const float* bptr[2]; int b_dst[2];
    #pragma unroll
    for (int q = 0; q < 2; ++q) {
        const int v = t + q * 512, oc = v & 127, kk = (v >> 7) * 4, z = oc >> 6;
        bptr[q] = W + (size_t)(z * 768 + kk) * 768 + (o0 + (oc & 63));
        b_dst[q] = (oc >> 4) * 512 + (kk >> 3) * 128 + (oc & 15) * 8 + (kk & 7);
    }

    f4 rA[2]; float rB[2][4];
    #pragma unroll
    for (int q = 0; q < 2; ++q) {
        rA[q] = *(const f4*)(aptr[q]);
        #pragma unroll
        for (int j = 0; j < 4; ++j) rB[q][j] = bptr[q][(size_t)j * 768];
    }

    f32x4 acc[4] = {0, 0, 0, 0};
    for (int c = 0; c < NCHUNK; ++c) {
        #pragma unroll
        for (int q = 0; q < 2; ++q) {
            u16x4 h, l;
            #pragma unroll
            for (int j = 0; j < 4; ++j) { h[j] = f2bf(rA[q][j]); l[j] = f2bf(rA[q][j] - bf2f(h[j])); }
            *(u16x4*)&u.s.Ah[a_dst[q]] = h; *(u16x4*)&u.s.Al[a_dst[q]] = l;
        }
        #pragma unroll
        for (int q = 0; q < 2; ++q) {
            u16x4 h, l;
            #pragma unroll
            for (int j = 0; j < 4; ++j) { h[j] = f2bf(rB[q][j]); l[j] = f2bf(rB[q][j] - bf2f(h[j])); }
            *(u16x4*)&u.s.Bh[b_dst[q]] = h; *(u16x4*)&u.s.Bl[b_dst[q]] = l;
        }
        __syncthreads();
        if (c + 1 < NCHUNK) {
            const int k0 = (c + 1) * 32;
            #pragma unroll
            for (int q = 0; q < 2; ++q) {
                rA[q] = *(const f4*)(aptr[q] + k0);
                #pragma unroll
                for (int j = 0; j < 4; ++j) rB[q][j] = bptr[q][(size_t)(k0 + j) * 768];
            }
        }
        {
            const short8 ah = *(const short8*)&u.s.Ah[w * 512 + lane * 8];
            const short8 al = *(const short8*)&u.s.Al[w * 512 + lane * 8];
            const int bt0 = (w >> 2) * 4;
            #pragma unroll
            for (int ct = 0; ct < 4; ++ct) {
                const short8 bh = *(const short8*)&u.s.Bh[(bt0 + ct) * 512 + lane * 8];
                const short8 bl = *(const short8*)&u.s.Bl[(bt0 + ct) * 512 + lane * 8];
                acc[ct] = __builtin_amdgcn_mfma_f32_16x16x32_bf16(ah, bh, acc[ct], 0, 0, 0);
                acc[ct] = __builtin_amdgcn_mfma_f32_16x16x32_bf16(ah, bl, acc[ct], 0, 0, 0);
                acc[ct] = __builtin_amdgcn_mfma_f32_16x16x32_bf16(al, bh, acc[ct], 0, 0, 0);
            }
        }
        __syncthreads();
    }
    #pragma unroll
    for (int ct = 0; ct < 4; ++ct)
        #pragma unroll
        for (int i = 0; i < 4; ++i)
            u.p[w * 16 + (lane >> 4) * 4 + i][ct * 16 + (lane & 15)] = acc[ct][i];
    __syncthreads();

    const int o4 = (t & 15) * 4, nn = t >> 4;
    const f4 bb  = *(const f4*)(bias + o0 + o4);
    const f4 p1a = *(const f4*)&u.p[nn * 2 + 0][o4] + bb;
    const f4 p1b = *(const f4*)&u.p[nn * 2 + 1][o4] + bb;
    float* ob = out + ((size_t)(b * 128 + n0 + nn * 2) * 128 + m0) * 768 + o0 + o4;
    const size_t nstride = (size_t)128 * 768;
    #pragma unroll 4
    for (int m = 0; m < 64; ++m) {
        const f4 p2v = *(const f4*)&u.p[64 + m][o4];
        __builtin_nontemporal_store(p1a + p2v, (f4*)(ob + (size_t)m * 768));
        __builtin_nontemporal_store(p1b + p2v, (f4*)(ob + nstride + (size_t)m * 768));
    }
}

extern "C" void kernel_launch(void* const* d_in, const int* in_sizes, int n_in,
                              void* d_out, int out_size, void* d_ws, size_t ws_size,
                              hipStream_t stream)
{
    const float* input1 = (const float*)d_in[0];  // (4,128,768)
    const float* input2 = (const float*)d_in[1];  // (4,128,768)
    const float* W      = (const float*)d_in[2];  // (1536,768)
    const float* bias   = (const float*)d_in[3];  // (768,)
    float* out = (float*)d_out;                   // (4,128,128,768)

    const size_t need = (size_t)(AWS_U16 + WWS_U16) * sizeof(u16);  // 7.86 MB

    if (ws_size >= need) {
        u16* Aws = (u16*)d_ws;
        u16* Wws = Aws + AWS_U16;
        convert_kernel<<<dim3(960), 512, 0, stream>>>(input1, input2, W, Aws, Wws);
        mfma_direct_kernel<<<dim3(12, 16), 512, 0, stream>>>(Aws, Wws, bias, out);
    } else {
        fused_v6<<<dim3(12, 16), 512, 0, stream>>>(input1, input2, W, bias, out);
    }
}

// Round 9
// 245.425 us; speedup vs baseline: 1.0017x; 1.0017x over previous
//
#include <hip/hip_runtime.h>

typedef float f4    __attribute__((ext_vector_type(4)));
typedef float f32x4 __attribute__((ext_vector_type(4)));
typedef short short8 __attribute__((ext_vector_type(8)));
typedef unsigned short u16;
typedef unsigned short u16x4 __attribute__((ext_vector_type(4)));

#define NCHUNK 24   // 768 k / 32 per chunk

// ---- ws fragment layouts (u16 units) — R7/R8-verified ----
// A_ws[g:16][c:24][hl:2][rt:4][kq:4][r:16][ki:8]  (g 0-7 = A1 rows/64, 8-15 = A2 rows/64)
// W_ws[c:24][panel:2][hl:2][rt:48][kq:4][r:16][ki:8]
#define AWS_U16 1572864u   // 3.0 MB
#define WWS_U16 2359296u   // 4.5 MB
#define P_FLOATS ((size_t)1024 * 768)   // 3.0 MB

__device__ inline u16 f2bf(float x) {
    union { float f; unsigned u; } v; v.f = x;
    return (u16)((v.u + 0x7FFFu + ((v.u >> 16) & 1u)) >> 16);
}
__device__ inline float bf2f(u16 h) {
    union { unsigned u; float f; } v; v.u = ((unsigned)h) << 16;
    return v.f;
}

// Streaming pre-convert (R7-verbatim, verified): f32 -> bf16 hi/lo in fragment order.
__global__ __launch_bounds__(512) void convert_kernel(
    const float* __restrict__ A1, const float* __restrict__ A2,
    const float* __restrict__ W, u16* __restrict__ Aws, u16* __restrict__ Wws)
{
    const int id = blockIdx.x * 512 + threadIdx.x;
    if (blockIdx.x < 384) {
        const int u   = id;
        const int row = u / 192;
        const int k   = (u - row * 192) * 4;
        const float* src = (row < 512) ? (A1 + (size_t)row * 768 + k)
                                       : (A2 + (size_t)(row - 512) * 768 + k);
        const f4 v = *(const f4*)src;
        u16x4 h, l;
        #pragma unroll
        for (int j = 0; j < 4; ++j) { h[j] = f2bf(v[j]); l[j] = f2bf(v[j] - bf2f(h[j])); }
        const int g = row >> 6, rt = (row >> 4) & 3, r = row & 15;
        const int c = k >> 5, kq = (k >> 3) & 3, ki0 = k & 7;
        const size_t base = (size_t)g * 98304 + c * 4096 + rt * 512 + kq * 128 + r * 8 + ki0;
        *(u16x4*)&Aws[base]        = h;
        *(u16x4*)&Aws[base + 2048] = l;
    } else {
        const int u   = id - 384 * 512;
        const int o   = u % 768;
        const int kk4 = u / 768;
        const int kk  = kk4 * 4;
        const int z   = (kk4 >= 192);
        const int k   = kk - z * 768;
        u16x4 h, l;
        #pragma unroll
        for (int j = 0; j < 4; ++j) {
            const float v = W[(size_t)(kk + j) * 768 + o];
            h[j] = f2bf(v); l[j] = f2bf(v - bf2f(h[j]));
        }
        const int rt = o >> 4, r = o & 15;
        const int c = k >> 5, kq = (k >> 3) & 3, ki0 = k & 7;
        const size_t base = (size_t)c * 98304 + (size_t)z * 49152
                          + rt * 512 + kq * 128 + r * 8 + ki0;
        *(u16x4*)&Wws[base]         = h;
        *(u16x4*)&Wws[base + 24576] = l;
    }
}

// MFMA GEMM -> P[1024][768] (rows 0-511: p1 = A1@W1; rows 512-1023: p2 = A2@W2 + bias).
// R8's proven barrier-free, LDS-free direct-from-ws MFMA core; grid deduplicated to
// 12 o-slices x 8 row-groups = 96 blocks (each row-group computed exactly once).
// R8 post-mortem: GEMM phase is ~15us and was never the bottleneck — egress was.
// Writing the 3 MB P here (stays L2-resident) and handing egress to a 2048-block
// kernel lets the 201 MB output stream use ALL 256 CUs instead of 192.
__global__ __launch_bounds__(512) void mfma_p_kernel(
    const u16* __restrict__ Aws, const u16* __restrict__ Wws,
    const float* __restrict__ bias, float* __restrict__ P)
{
    const int o0 = blockIdx.x * 64;         // 12 o-slices
    const int z  = blockIdx.y;              // 8 row-groups
    const int t = threadIdx.x, lane = t & 63, w = t >> 6;
    const int rt0 = blockIdx.x * 4;

    // waves 0-3: A1 group z (P rows z*64..); waves 4-7: A2 group 8+z (P rows 512+z*64..)
    const u16* aBase = Aws + (size_t)((w < 4) ? z : 8 + z) * 98304
                     + (w & 3) * 512 + lane * 8;
    const u16* bBase = Wws + (size_t)((w < 4) ? 0 : 1) * 49152
                     + rt0 * 512 + lane * 8;

    f32x4 acc[4] = {0, 0, 0, 0};

    #pragma unroll 2
    for (int c = 0; c < NCHUNK; ++c) {
        const u16* ap = aBase + (size_t)c * 4096;
        const u16* bp = bBase + (size_t)c * 98304;
        const short8 ah = *(const short8*)(ap);
        const short8 al = *(const short8*)(ap + 2048);
        #pragma unroll
        for (int ct = 0; ct < 4; ++ct) {
            const short8 bh = *(const short8*)(bp + ct * 512);
            const short8 bl = *(const short8*)(bp + 24576 + ct * 512);
            acc[ct] = __builtin_amdgcn_mfma_f32_16x16x32_bf16(ah, bh, acc[ct], 0, 0, 0);
            acc[ct] = __builtin_amdgcn_mfma_f32_16x16x32_bf16(ah, bl, acc[ct], 0, 0, 0);
            acc[ct] = __builtin_amdgcn_mfma_f32_16x16x32_bf16(al, bh, acc[ct], 0, 0, 0);
        }
    }

    // fold bias into p2 rows (w>=4) so bcast is pure add
    const int col = o0 + (lane & 15);
    if (w >= 4) {
        #pragma unroll
        for (int ct = 0; ct < 4; ++ct) {
            const float bv = bias[col + ct * 16];
            #pragma unroll
            for (int i = 0; i < 4; ++i) acc[ct][i] += bv;
        }
    }

    // store C (verified D mapping: row=(lane>>4)*4+i, col=lane&15)
    const int row0 = ((w < 4) ? z * 64 : 512 + z * 64) + (w & 3) * 16 + (lane >> 4) * 4;
    #pragma unroll
    for (int ct = 0; ct < 4; ++ct)
        #pragma unroll
        for (int i = 0; i < 4; ++i)
            P[(size_t)(row0 + i) * 768 + col + ct * 16] = acc[ct][i];
}

// Egress (R1-proven structure): out[b,n,m,:] = P[b*128+n,:] + P[512+b*128+m,:]
// 2048 blocks x 192 threads -> all 256 CUs write; 201 MB NT stream at ~full BW.
// P (3 MB) is L2-resident per XCD (< 4 MiB).
__global__ __launch_bounds__(192) void bcast_kernel(
    const float* __restrict__ P, float* __restrict__ out)
{
    const int t     = threadIdx.x;       // 0..191
    const int bn    = blockIdx.x;        // 0..511 = b*128+n
    const int b     = bn >> 7;
    const int mbase = blockIdx.y * 32;

    const f4 p1v = *(const f4*)(P + (size_t)bn * 768 + t * 4);
    const float* p2base = P + (size_t)(512 + b * 128) * 768 + t * 4;
    float* obase = out + (size_t)bn * (128 * 768) + t * 4;

    #pragma unroll 4
    for (int mm = 0; mm < 32; ++mm) {
        const int m = mbase + mm;
        const f4 v = p1v + *(const f4*)(p2base + (size_t)m * 768);
        __builtin_nontemporal_store(v, (f4*)(obase + (size_t)m * 768));
    }
}

// ---------------- fallback: R6 kernel verbatim (passed @ absmax 0.015625) ----------------
__global__ __launch_bounds__(512) void fused_v6(
    const float* __restrict__ A1, const float* __restrict__ A2,
    const float* __restrict__ W, const float* __restrict__ bias,
    float* __restrict__ out)
{
    __shared__ union {
        struct { u16 Ah[4096], Al[4096], Bh[4096], Bl[4096]; } s;
        float p[128][68];
    } u;

    const int o0 = blockIdx.x * 64;
    const int nm = blockIdx.y;
    const int b  = nm >> 2;
    const int n0 = ((nm >> 1) & 1) * 64;
    const int m0 = (nm & 1) * 64;
    const int t = threadIdx.x, lane = t & 63, w = t >> 6;

    const float* aptr[2]; int a_dst[2];
    #pragma unroll
    for (int q = 0; q < 2; ++q) {
        const int a = t + q * 512, rc = a >> 3, k0 = (a & 7) * 4;
        const float* base = (rc < 64) ? (A1 + (size_t)(b * 128 + n0 + rc) * 768)
                                      : (A2 + (size_t)(b * 128 + m0 + (rc - 64)) * 768);
        aptr[q] = base + k0;
        a_dst[q] = (rc >> 4) * 512 + (k0 >> 3) * 128 + (rc & 15) * 8 + (k0 & 7);
    }
    const float* bptr[2]; int b_dst[2];
    #pragma unroll
    for (int q = 0; q < 2; ++q) {
        const int v = t + q * 512, oc = v & 127, kk = (v >> 7) * 4, z = oc >> 6;
        bptr[q] = W + (size_t)(z * 768 + kk) * 768 + (o0 + (oc & 63));
        b_dst[q] = (oc >> 4) * 512 + (kk >> 3) * 128 + (oc & 15) * 8 + (kk & 7);
    }

    f4 rA[2]; float rB[2][4];
    #pragma unroll
    for (int q = 0; q < 2; ++q) {
        rA[q] = *(const f4*)(aptr[q]);
        #pragma unroll
        for (int j = 0; j < 4; ++j) rB[q][j] = bptr[q][(size_t)j * 768];
    }

    f32x4 acc[4] = {0, 0, 0, 0};
    for (int c = 0; c < NCHUNK; ++c) {
        #pragma unroll
        for (int q = 0; q < 2; ++q) {
            u16x4 h, l;
            #pragma unroll
            for (int j = 0; j < 4; ++j) { h[j] = f2bf(rA[q][j]); l[j] = f2bf(rA[q][j] - bf2f(h[j])); }
            *(u16x4*)&u.s.Ah[a_dst[q]] = h; *(u16x4*)&u.s.Al[a_dst[q]] = l;
        }
        #pragma unroll
        for (int q = 0; q < 2; ++q) {
            u16x4 h, l;
            #pragma unroll
            for (int j = 0; j < 4; ++j) { h[j] = f2bf(rB[q][j]); l[j] = f2bf(rB[q][j] - bf2f(h[j])); }
            *(u16x4*)&u.s.Bh[b_dst[q]] = h; *(u16x4*)&u.s.Bl[b_dst[q]] = l;
        }
        __syncthreads();
        if (c + 1 < NCHUNK) {
            const int k0 = (c + 1) * 32;
            #pragma unroll
            for (int q = 0; q < 2; ++q) {
                rA[q] = *(const f4*)(aptr[q] + k0);
                #pragma unroll
                for (int j = 0; j < 4; ++j) rB[q][j] = bptr[q][(size_t)(k0 + j) * 768];
            }
        }
        {
            const short8 ah = *(const short8*)&u.s.Ah[w * 512 + lane * 8];
            const short8 al = *(const short8*)&u.s.Al[w * 512 + lane * 8];
            const int bt0 = (w >> 2) * 4;
            #pragma unroll
            for (int ct = 0; ct < 4; ++ct) {
                const short8 bh = *(const short8*)&u.s.Bh[(bt0 + ct) * 512 + lane * 8];
                const short8 bl = *(const short8*)&u.s.Bl[(bt0 + ct) * 512 + lane * 8];
                acc[ct] = __builtin_amdgcn_mfma_f32_16x16x32_bf16(ah, bh, acc[ct], 0, 0, 0);
                acc[ct] = __builtin_amdgcn_mfma_f32_16x16x32_bf16(ah, bl, acc[ct], 0, 0, 0);
                acc[ct] = __builtin_amdgcn_mfma_f32_16x16x32_bf16(al, bh, acc[ct], 0, 0, 0);
            }
        }
        __syncthreads();
    }
    #pragma unroll
    for (int ct = 0; ct < 4; ++ct)
        #pragma unroll
        for (int i = 0; i < 4; ++i)
            u.p[w * 16 + (lane >> 4) * 4 + i][ct * 16 + (lane & 15)] = acc[ct][i];
    __syncthreads();

    const int o4 = (t & 15) * 4, nn = t >> 4;
    const f4 bb  = *(const f4*)(bias + o0 + o4);
    const f4 p1a = *(const f4*)&u.p[nn * 2 + 0][o4] + bb;
    const f4 p1b = *(const f4*)&u.p[nn * 2 + 1][o4] + bb;
    float* ob = out + ((size_t)(b * 128 + n0 + nn * 2) * 128 + m0) * 768 + o0 + o4;
    const size_t nstride = (size_t)128 * 768;
    #pragma unroll 4
    for (int m = 0; m < 64; ++m) {
        const f4 p2v = *(const f4*)&u.p[64 + m][o4];
        __builtin_nontemporal_store(p1a + p2v, (f4*)(ob + (size_t)m * 768));
        __builtin_nontemporal_store(p1b + p2v, (f4*)(ob + nstride + (size_t)m * 768));
    }
}

extern "C" void kernel_launch(void* const* d_in, const int* in_sizes, int n_in,
                              void* d_out, int out_size, void* d_ws, size_t ws_size,
                              hipStream_t stream)
{
    const float* input1 = (const float*)d_in[0];  // (4,128,768)
    const float* input2 = (const float*)d_in[1];  // (4,128,768)
    const float* W      = (const float*)d_in[2];  // (1536,768)
    const float* bias   = (const float*)d_in[3];  // (768,)
    float* out = (float*)d_out;                   // (4,128,128,768)

    const size_t need = (size_t)(AWS_U16 + WWS_U16) * sizeof(u16)
                      + P_FLOATS * sizeof(float);                   // 10.86 MB

    if (ws_size >= need) {
        u16* Aws = (u16*)d_ws;
        u16* Wws = Aws + AWS_U16;
        float* P = (float*)(Wws + WWS_U16);
        convert_kernel<<<dim3(960), 512, 0, stream>>>(input1, input2, W, Aws, Wws);
        mfma_p_kernel<<<dim3(12, 8), 512, 0, stream>>>(Aws, Wws, bias, P);
        bcast_kernel<<<dim3(512, 4), 192, 0, stream>>>(P, out);
    } else {
        fused_v6<<<dim3(12, 16), 512, 0, stream>>>(input1, input2, W, bias, out);
    }
}